// Round 1
// baseline (2510.323 us; speedup 1.0000x reference)
//
#include <hip/hip_runtime.h>
#include <hip/hip_bf16.h>

// Problem constants
#define M_ROWS 16384   // B
#define N_CODES 8192   // K
#define DDIM    512    // D

// GEMM tile
#define BM 64
#define BN 64
#define BK 16
#define LDT (BM + 4)   // padded LDS row stride (keeps 16B alignment)

__device__ __forceinline__ unsigned int float_to_ordered(float f) {
    unsigned int u = __float_as_uint(f);
    return (u & 0x80000000u) ? ~u : (u | 0x80000000u);
}

// ---------------------------------------------------------------------------
// Kernel 1: e_norms[k] = ||embedding[k]||^2.  One wave per code.
// ---------------------------------------------------------------------------
__global__ __launch_bounds__(256) void vq_enorm(const float* __restrict__ emb,
                                                float* __restrict__ e_norms) {
    int wave = threadIdx.x >> 6;
    int lane = threadIdx.x & 63;
    int code = blockIdx.x * 4 + wave;
    const float4* ep = (const float4*)(emb + (size_t)code * DDIM);
    float s = 0.f;
    #pragma unroll
    for (int j = 0; j < 2; ++j) {
        float4 e = ep[lane + 64 * j];
        s += e.x * e.x + e.y * e.y + e.z * e.z + e.w * e.w;
    }
    #pragma unroll
    for (int off = 32; off; off >>= 1) s += __shfl_down(s, off, 64);
    if (lane == 0) e_norms[code] = s;
}

// ---------------------------------------------------------------------------
// Kernel 2: tiled fp32 GEMM (dot = z . e) with fused argmin epilogue.
// dist = ||e||^2 - 2*dot  (row-constant ||z||^2 omitted; argmin-invariant).
// Cross-block merge: atomicMin on packed (ordered_dist << 32 | col) --
// reproduces argmin's first-index tie-break.
// ---------------------------------------------------------------------------
__global__ __launch_bounds__(256) void vq_argmin_gemm(
    const float* __restrict__ z, const float* __restrict__ emb,
    const float* __restrict__ e_norms,
    unsigned long long* __restrict__ packed) {
    __shared__ float As[BK][LDT];
    __shared__ float Bs[BK][LDT];
    __shared__ unsigned long long red[BM][16];

    const int tid  = threadIdx.x;
    const int row0 = blockIdx.x * BM;
    const int col0 = blockIdx.y * BN;

    // loader: 256 threads, one float4 of A and B per BK-chunk each
    const int lr = tid >> 2;          // 0..63 tile row
    const int lc = (tid & 3) << 2;    // 0,4,8,12 within chunk

    // compute: 16x16 thread grid, 4x4 outputs each
    const int tmg = tid & 15;         // row group
    const int tng = tid >> 4;         // col group
    const int tm  = tmg << 2;
    const int tn  = tng << 2;

    float acc[4][4] = {};

    const float* zP = z   + (size_t)(row0 + lr) * DDIM + lc;
    const float* eP = emb + (size_t)(col0 + lr) * DDIM + lc;

    for (int d0 = 0; d0 < DDIM; d0 += BK) {
        float4 a4 = *(const float4*)(zP + d0);
        float4 b4 = *(const float4*)(eP + d0);
        __syncthreads();
        As[lc + 0][lr] = a4.x; As[lc + 1][lr] = a4.y;
        As[lc + 2][lr] = a4.z; As[lc + 3][lr] = a4.w;
        Bs[lc + 0][lr] = b4.x; Bs[lc + 1][lr] = b4.y;
        Bs[lc + 2][lr] = b4.z; Bs[lc + 3][lr] = b4.w;
        __syncthreads();
        #pragma unroll
        for (int kk = 0; kk < BK; ++kk) {
            float4 av = *(const float4*)(&As[kk][tm]);
            float4 bv = *(const float4*)(&Bs[kk][tn]);
            float a[4] = {av.x, av.y, av.z, av.w};
            float b[4] = {bv.x, bv.y, bv.z, bv.w};
            #pragma unroll
            for (int i = 0; i < 4; ++i)
                #pragma unroll
                for (int j = 0; j < 4; ++j)
                    acc[i][j] += a[i] * b[j];
        }
    }

    // epilogue: per-thread argmin over its 4 cols, per row
    float en[4];
    #pragma unroll
    for (int j = 0; j < 4; ++j) en[j] = e_norms[col0 + tn + j];

    #pragma unroll
    for (int i = 0; i < 4; ++i) {
        float bd = __builtin_inff();
        int   bc = 0;
        #pragma unroll
        for (int j = 0; j < 4; ++j) {
            float dist = en[j] - 2.0f * acc[i][j];
            if (dist < bd) { bd = dist; bc = col0 + tn + j; }  // strict < keeps first
        }
        red[tm + i][tng] =
            ((unsigned long long)float_to_ordered(bd) << 32) | (unsigned int)bc;
    }
    __syncthreads();
    if (tid < BM) {
        unsigned long long m = red[tid][0];
        #pragma unroll
        for (int t = 1; t < 16; ++t) {
            unsigned long long v = red[tid][t];
            m = (v < m) ? v : m;
        }
        atomicMin(&packed[row0 + tid], m);
    }
}

// ---------------------------------------------------------------------------
// Kernel 3: gather quantized rows, write float indices, per-block loss partial.
// One wave per row, 4 rows per block.
// ---------------------------------------------------------------------------
__global__ __launch_bounds__(256) void vq_gather_loss(
    const float* __restrict__ z, const float* __restrict__ emb,
    const unsigned long long* __restrict__ packed,
    float* __restrict__ out_q, float* __restrict__ out_idx,
    float* __restrict__ partials) {
    int wave = threadIdx.x >> 6;
    int lane = threadIdx.x & 63;
    int row  = blockIdx.x * 4 + wave;

    int idx = (int)(packed[row] & 0xFFFFFFFFull);
    const float4* qp = (const float4*)(emb + (size_t)idx * DDIM);
    const float4* zp = (const float4*)(z + (size_t)row * DDIM);
    float4*       op = (float4*)(out_q + (size_t)row * DDIM);

    float local = 0.f;
    #pragma unroll
    for (int j = 0; j < 2; ++j) {
        int c = lane + 64 * j;
        float4 q = qp[c];
        float4 v = zp[c];
        op[c] = q;
        float dx = v.x - q.x, dy = v.y - q.y, dz = v.z - q.z, dw = v.w - q.w;
        local += dx * dx + dy * dy + dz * dz + dw * dw;
    }
    #pragma unroll
    for (int off = 32; off; off >>= 1) local += __shfl_down(local, off, 64);

    __shared__ float wsum[4];
    if (lane == 0) { wsum[wave] = local; out_idx[row] = (float)idx; }
    __syncthreads();
    if (threadIdx.x == 0)
        partials[blockIdx.x] = wsum[0] + wsum[1] + wsum[2] + wsum[3];
}

// ---------------------------------------------------------------------------
// Kernel 4: reduce 4096 loss partials -> scalar loss.
// ---------------------------------------------------------------------------
__global__ __launch_bounds__(256) void vq_finalize(const float* __restrict__ partials,
                                                   float* __restrict__ out_loss) {
    __shared__ float red[256];
    float s = 0.f;
    for (int i = threadIdx.x; i < 4096; i += 256) s += partials[i];
    red[threadIdx.x] = s;
    __syncthreads();
    for (int off = 128; off; off >>= 1) {
        if (threadIdx.x < off) red[threadIdx.x] += red[threadIdx.x + off];
        __syncthreads();
    }
    if (threadIdx.x == 0)
        out_loss[0] = 0.25f * red[0] / ((float)M_ROWS * (float)DDIM);
}

extern "C" void kernel_launch(void* const* d_in, const int* in_sizes, int n_in,
                              void* d_out, int out_size, void* d_ws, size_t ws_size,
                              hipStream_t stream) {
    const float* z   = (const float*)d_in[0];   // [16384, 512]
    const float* emb = (const float*)d_in[1];   // [8192, 512]

    float* out      = (float*)d_out;
    float* out_q    = out;                                  // 16384*512
    float* out_idx  = out + (size_t)M_ROWS * DDIM;          // 16384 (as float)
    float* out_loss = out + (size_t)M_ROWS * DDIM + M_ROWS; // 1

    // workspace layout
    float* e_norms = (float*)d_ws;                                         // 32 KB
    unsigned long long* packed =
        (unsigned long long*)((char*)d_ws + 32768);                        // 128 KB
    float* partials = (float*)((char*)d_ws + 32768 + 131072);              // 16 KB

    hipMemsetAsync(packed, 0xFF, (size_t)M_ROWS * 8, stream);

    vq_enorm<<<N_CODES / 4, 256, 0, stream>>>(emb, e_norms);
    vq_argmin_gemm<<<dim3(M_ROWS / BM, N_CODES / BN), 256, 0, stream>>>(
        z, emb, e_norms, packed);
    vq_gather_loss<<<M_ROWS / 4, 256, 0, stream>>>(z, emb, packed, out_q, out_idx,
                                                   partials);
    vq_finalize<<<1, 256, 0, stream>>>(partials, out_loss);
}

// Round 2
// 519.695 us; speedup vs baseline: 4.8304x; 4.8304x over previous
//
#include <hip/hip_runtime.h>
#include <hip/hip_bf16.h>

#define M_ROWS 16384
#define N_CODES 8192
#define DDIM    512

typedef unsigned int u32;
typedef unsigned long long u64;
typedef unsigned short u16;
typedef __attribute__((ext_vector_type(8))) short short8;   // 8 bf16 = 4 VGPRs
typedef __attribute__((ext_vector_type(4))) float f32x4;

__device__ __forceinline__ u32 float_to_ordered(float f) {
    u32 u = __float_as_uint(f);
    return (u & 0x80000000u) ? ~u : (u | 0x80000000u);
}

__device__ __forceinline__ u16 bf16_rne(float x) {
    u32 u = __float_as_uint(x);
    u32 r = u + 0x7FFFu + ((u >> 16) & 1u);
    return (u16)(r >> 16);
}

__device__ __forceinline__ void gl_lds16(const void* g, void* l) {
    // 16B/lane direct global->LDS; dest is wave-uniform base + lane*16
    __builtin_amdgcn_global_load_lds((const __attribute__((address_space(1))) u32*)g,
                                     (__attribute__((address_space(3))) u32*)l,
                                     16, 0, 0);
}

__device__ __forceinline__ u64 umin64(u64 a, u64 b) { return a < b ? a : b; }

// ---------------------------------------------------------------------------
// Kernel 1: split fp32 -> (hi, lo) bf16 arrays. 4 floats/thread.
// ---------------------------------------------------------------------------
__global__ __launch_bounds__(256) void vq_split(const float4* __restrict__ src,
                                                ushort4* __restrict__ hi,
                                                ushort4* __restrict__ lo) {
    int i = blockIdx.x * 256 + threadIdx.x;
    float4 v = src[i];
    ushort4 h, l;
    h.x = bf16_rne(v.x); h.y = bf16_rne(v.y); h.z = bf16_rne(v.z); h.w = bf16_rne(v.w);
    l.x = bf16_rne(v.x - __uint_as_float((u32)h.x << 16));
    l.y = bf16_rne(v.y - __uint_as_float((u32)h.y << 16));
    l.z = bf16_rne(v.z - __uint_as_float((u32)h.z << 16));
    l.w = bf16_rne(v.w - __uint_as_float((u32)h.w << 16));
    hi[i] = h; lo[i] = l;
}

// ---------------------------------------------------------------------------
// Kernel 2: e_norms[k] = ||embedding[k]||^2 (fp32). One wave per code.
// ---------------------------------------------------------------------------
__global__ __launch_bounds__(256) void vq_enorm(const float* __restrict__ emb,
                                                float* __restrict__ e_norms) {
    int wave = threadIdx.x >> 6;
    int lane = threadIdx.x & 63;
    int code = blockIdx.x * 4 + wave;
    const float4* ep = (const float4*)(emb + (size_t)code * DDIM);
    float s = 0.f;
    #pragma unroll
    for (int j = 0; j < 2; ++j) {
        float4 e = ep[lane + 64 * j];
        s += e.x * e.x + e.y * e.y + e.z * e.z + e.w * e.w;
    }
    #pragma unroll
    for (int off = 32; off; off >>= 1) s += __shfl_down(s, off, 64);
    if (lane == 0) e_norms[code] = s;
}

// ---------------------------------------------------------------------------
// Kernel 3: MFMA distance GEMM + fused argmin.
// dot = z.e via split-bf16 3x mfma_f32_16x16x32_bf16; dist = ||e||^2 - 2*dot.
// 128x128 block tile, BK=32, 4 waves (2x2), 64x64 per wave (4x4 frags).
// ---------------------------------------------------------------------------
__global__ __launch_bounds__(256) void vq_mfma_argmin(
    const u16* __restrict__ z_hi, const u16* __restrict__ z_lo,
    const u16* __restrict__ e_hi, const u16* __restrict__ e_lo,
    const float* __restrict__ e_norms,
    u64* __restrict__ packed) {
    // 4 tiles x [128 rows][32 k] bf16 = 4 x 8 KB
    __shared__ __align__(16) u16 ldsAh[128][32];
    __shared__ __align__(16) u16 ldsAl[128][32];
    __shared__ __align__(16) u16 ldsBh[128][32];
    __shared__ __align__(16) u16 ldsBl[128][32];
    __shared__ u64 redL[2][128];

    const int tid  = threadIdx.x;
    const int wave = tid >> 6;
    const int lane = tid & 63;
    const int wm   = wave & 1;   // row half
    const int wn   = wave >> 1;  // col half
    const int row0 = blockIdx.x * 128;
    const int col0 = blockIdx.y * 128;

    // staging: lane -> (row wave*32 + (lane>>2) [+16], elems (lane&3)*8)
    const int srow = (wave << 5) + (lane >> 2);
    const int scol = (lane & 3) << 3;
    const u16* gAh = z_hi + (size_t)(row0 + srow) * DDIM + scol;
    const u16* gAl = z_lo + (size_t)(row0 + srow) * DDIM + scol;
    const u16* gBh = e_hi + (size_t)(col0 + srow) * DDIM + scol;
    const u16* gBl = e_lo + (size_t)(col0 + srow) * DDIM + scol;

    // fragment read coords
    const int fm = (wm << 6) + (lane & 15);   // + i*16 -> A row in tile
    const int fn = (wn << 6) + (lane & 15);   // + j*16 -> B row in tile
    const int fk = (lane >> 4) << 3;          // k element offset (8 bf16 = 16B)

    f32x4 acc[4][4] = {};

    for (int it = 0; it < 16; ++it) {
        const int d0 = it << 5;
        __syncthreads();
        #pragma unroll
        for (int s = 0; s < 2; ++s) {
            const size_t go = (size_t)d0 + (size_t)s * 16 * DDIM;
            const int lr = (wave << 5) + (s << 4);
            gl_lds16(gAh + go, &ldsAh[lr][0]);
            gl_lds16(gAl + go, &ldsAl[lr][0]);
            gl_lds16(gBh + go, &ldsBh[lr][0]);
            gl_lds16(gBl + go, &ldsBl[lr][0]);
        }
        __syncthreads();   // drains vmcnt(0) + barrier

        short8 ah[4], al[4], bh[4], bl[4];
        #pragma unroll
        for (int i = 0; i < 4; ++i) {
            ah[i] = *(const short8*)&ldsAh[fm + i * 16][fk];
            al[i] = *(const short8*)&ldsAl[fm + i * 16][fk];
        }
        #pragma unroll
        for (int j = 0; j < 4; ++j) {
            bh[j] = *(const short8*)&ldsBh[fn + j * 16][fk];
            bl[j] = *(const short8*)&ldsBl[fn + j * 16][fk];
        }
        #pragma unroll
        for (int i = 0; i < 4; ++i)
            #pragma unroll
            for (int j = 0; j < 4; ++j) {
                acc[i][j] = __builtin_amdgcn_mfma_f32_16x16x32_bf16(ah[i], bh[j], acc[i][j], 0, 0, 0);
                acc[i][j] = __builtin_amdgcn_mfma_f32_16x16x32_bf16(ah[i], bl[j], acc[i][j], 0, 0, 0);
                acc[i][j] = __builtin_amdgcn_mfma_f32_16x16x32_bf16(al[i], bh[j], acc[i][j], 0, 0, 0);
            }
    }

    // epilogue: C layout col = lane&15, row = (lane>>4)*4 + reg
    const int cn = (lane & 15);
    const int cg = (lane >> 4);
    float en[4];
    #pragma unroll
    for (int j = 0; j < 4; ++j) en[j] = e_norms[col0 + (wn << 6) + j * 16 + cn];

    #pragma unroll
    for (int i = 0; i < 4; ++i)
        #pragma unroll
        for (int r = 0; r < 4; ++r) {
            u64 best = 0xFFFFFFFFFFFFFFFFull;
            #pragma unroll
            for (int j = 0; j < 4; ++j) {
                float dist = en[j] - 2.0f * acc[i][j][r];
                u64 p = ((u64)float_to_ordered(dist) << 32)
                        | (u32)(col0 + (wn << 6) + j * 16 + cn);
                best = umin64(best, p);
            }
            #pragma unroll
            for (int off = 1; off < 16; off <<= 1)
                best = umin64(best, __shfl_xor(best, off, 64));
            if (cn == 0)
                redL[wn][(wm << 6) + (i << 4) + (cg << 2) + r] = best;
        }
    __syncthreads();
    if (tid < 128) {
        u64 m = umin64(redL[0][tid], redL[1][tid]);
        atomicMin(&packed[row0 + tid], m);
    }
}

// ---------------------------------------------------------------------------
// Kernel 4: gather quantized rows, float indices, per-block loss partial.
// ---------------------------------------------------------------------------
__global__ __launch_bounds__(256) void vq_gather_loss(
    const float* __restrict__ z, const float* __restrict__ emb,
    const u64* __restrict__ packed,
    float* __restrict__ out_q, float* __restrict__ out_idx,
    float* __restrict__ partials) {
    int wave = threadIdx.x >> 6;
    int lane = threadIdx.x & 63;
    int row  = blockIdx.x * 4 + wave;

    int idx = (int)(packed[row] & 0xFFFFFFFFull);
    const float4* qp = (const float4*)(emb + (size_t)idx * DDIM);
    const float4* zp = (const float4*)(z + (size_t)row * DDIM);
    float4*       op = (float4*)(out_q + (size_t)row * DDIM);

    float local = 0.f;
    #pragma unroll
    for (int j = 0; j < 2; ++j) {
        int c = lane + 64 * j;
        float4 q = qp[c];
        float4 v = zp[c];
        op[c] = q;
        float dx = v.x - q.x, dy = v.y - q.y, dz = v.z - q.z, dw = v.w - q.w;
        local += dx * dx + dy * dy + dz * dz + dw * dw;
    }
    #pragma unroll
    for (int off = 32; off; off >>= 1) local += __shfl_down(local, off, 64);

    __shared__ float wsum[4];
    if (lane == 0) { wsum[wave] = local; out_idx[row] = (float)idx; }
    __syncthreads();
    if (threadIdx.x == 0)
        partials[blockIdx.x] = wsum[0] + wsum[1] + wsum[2] + wsum[3];
}

__global__ __launch_bounds__(256) void vq_finalize(const float* __restrict__ partials,
                                                   float* __restrict__ out_loss) {
    __shared__ float red[256];
    float s = 0.f;
    for (int i = threadIdx.x; i < 4096; i += 256) s += partials[i];
    red[threadIdx.x] = s;
    __syncthreads();
    for (int off = 128; off; off >>= 1) {
        if (threadIdx.x < off) red[threadIdx.x] += red[threadIdx.x + off];
        __syncthreads();
    }
    if (threadIdx.x == 0)
        out_loss[0] = 0.25f * red[0] / ((float)M_ROWS * (float)DDIM);
}

extern "C" void kernel_launch(void* const* d_in, const int* in_sizes, int n_in,
                              void* d_out, int out_size, void* d_ws, size_t ws_size,
                              hipStream_t stream) {
    const float* z   = (const float*)d_in[0];   // [16384, 512]
    const float* emb = (const float*)d_in[1];   // [8192, 512]

    float* out      = (float*)d_out;
    float* out_q    = out;
    float* out_idx  = out + (size_t)M_ROWS * DDIM;
    float* out_loss = out + (size_t)M_ROWS * DDIM + M_ROWS;

    char* ws = (char*)d_ws;
    u64*   packed   = (u64*)ws;                       // 128 KB
    float* e_norms  = (float*)(ws + 131072);          // 32 KB
    float* partials = (float*)(ws + 163840);          // 16 KB

    const size_t zbytes = (size_t)M_ROWS * DDIM * 2;   // 16 MB per half
    const size_t ebytes = (size_t)N_CODES * DDIM * 2;  // 8 MB per half
    const size_t base = 196608;
    u16 *z_hi, *z_lo, *e_hi, *e_lo;
    if (ws_size >= base + 2 * zbytes + 2 * ebytes) {
        z_hi = (u16*)(ws + base);
        z_lo = (u16*)(ws + base + zbytes);
        e_hi = (u16*)(ws + base + 2 * zbytes);
        e_lo = (u16*)(ws + base + 2 * zbytes + ebytes);
    } else {
        // stash z halves in the out_q region (32 MB, rewritten by gather later)
        z_hi = (u16*)out_q;
        z_lo = (u16*)((char*)out_q + zbytes);
        e_hi = (u16*)(ws + base);
        e_lo = (u16*)(ws + base + ebytes);
    }

    hipMemsetAsync(packed, 0xFF, (size_t)M_ROWS * 8, stream);

    vq_split<<<(M_ROWS * DDIM) / 1024, 256, 0, stream>>>(
        (const float4*)z, (ushort4*)z_hi, (ushort4*)z_lo);
    vq_split<<<(N_CODES * DDIM) / 1024, 256, 0, stream>>>(
        (const float4*)emb, (ushort4*)e_hi, (ushort4*)e_lo);
    vq_enorm<<<N_CODES / 4, 256, 0, stream>>>(emb, e_norms);

    vq_mfma_argmin<<<dim3(M_ROWS / 128, N_CODES / 128), 256, 0, stream>>>(
        z_hi, z_lo, e_hi, e_lo, e_norms, packed);

    vq_gather_loss<<<M_ROWS / 4, 256, 0, stream>>>(z, emb, packed, out_q, out_idx,
                                                   partials);
    vq_finalize<<<1, 256, 0, stream>>>(partials, out_loss);
}